// Round 14
// baseline (328.241 us; speedup 1.0000x reference)
//
#include <hip/hip_runtime.h>
#include <math.h>

#define VV 2048
#define BIGC 1e9f

__device__ __forceinline__ float wsum64(float v){
  v += __shfl_xor(v, 1, 64);
  v += __shfl_xor(v, 2, 64);
  v += __shfl_xor(v, 4, 64);
  v += __shfl_xor(v, 8, 64);
  v += __shfl_xor(v, 16, 64);
  v += __shfl_xor(v, 32, 64);
  return v;
}
__device__ __forceinline__ float gmax16(float v){
  v = fmaxf(v, __shfl_xor(v, 1, 16));
  v = fmaxf(v, __shfl_xor(v, 2, 16));
  v = fmaxf(v, __shfl_xor(v, 4, 16));
  v = fmaxf(v, __shfl_xor(v, 8, 16));
  return v;
}
__device__ __forceinline__ float gsum16(float v){
  v += __shfl_xor(v, 1, 16);
  v += __shfl_xor(v, 2, 16);
  v += __shfl_xor(v, 4, 16);
  v += __shfl_xor(v, 8, 16);
  return v;
}
__device__ __forceinline__ float sigm(float x){ return 1.f/(1.f+expf(-x)); }

// 8 rows/wave mapping: batch = blk&7 (XCD round-robin), slot = blk>>3 in [0,64)
__device__ __forceinline__ int xcd_base8(int blk, int wid){
  int b = blk & 7, slot = blk >> 3;
  return b*VV + slot*32 + wid*8;
}

// ---------------- K_emb: batch-independent encoder part P[u] = emb_c[u]@encW[:32] + encb ----------------
__global__ void __launch_bounds__(256,2)
k_emb(const float* __restrict__ emb, const float* __restrict__ encW,
      const float* __restrict__ encb, float* __restrict__ P)
{
  __shared__ float EC[4][256];
  int wid = threadIdx.x>>6, lane = threadIdx.x&63;
  int base = blockIdx.x*32 + wid*8;
  #pragma unroll
  for(int r=0;r<8;r++){
    int u = base+r;
    float ev = (lane < 32) ? emb[u*32 + lane] : 0.f;
    float ss = wsum64(ev*ev);
    float sc = (ss > 1.f) ? 1.f/sqrtf(ss) : 1.f;
    if(lane < 32) EC[wid][r*32+lane] = ev*sc;
  }
  float acc[8];
  #pragma unroll
  for(int r=0;r<8;r++) acc[r] = encb[lane];
  for(int k=0;k<32;k++){
    float wv = encW[k*64+lane];
    #pragma unroll
    for(int r=0;r<8;r++) acc[r] += EC[wid][r*32+k]*wv;
  }
  #pragma unroll
  for(int r=0;r<8;r++) P[(base+r)*64+lane] = acc[r];
}

// ---------------- K_enc: per-node encoder (feat part + P) + H1/sH1 (+ folded init in block 0) ----------------
// C layout: [0:64) s1m | [64:128) h2m | [128] sh2m | [384:448) s2m | [448] nwm
__global__ void __launch_bounds__(256,2)
k_enc(const float* __restrict__ feat, const float* __restrict__ P,
      const float* __restrict__ encW,
      const float* __restrict__ gatW, const float* __restrict__ gatb,
      const float* __restrict__ gata,
      const float* __restrict__ gruWh, const float* __restrict__ grub,
      const float* __restrict__ dW1, const float* __restrict__ db1,
      const float* __restrict__ dW2, const float* __restrict__ db2,
      float* __restrict__ enc, float* __restrict__ HH,
      float* __restrict__ sHH, float* __restrict__ out, float* __restrict__ C)
{
  __shared__ float IN[4][128];
  __shared__ float E[4][512];
  __shared__ float hmL[3][64];
  int wid = threadIdx.x >> 6, lane = threadIdx.x & 63;
  int base = xcd_base8(blockIdx.x, wid);
  #pragma unroll
  for(int r=0;r<8;r++){
    int row = base+r;
    if(lane < 16) IN[wid][r*16+lane] = feat[row*16 + lane];
  }
  float acc[8];
  #pragma unroll
  for(int r=0;r<8;r++){
    int u = (base+r) & (VV-1);
    acc[r] = P[u*64+lane];
  }
  for(int k=0;k<16;k++){
    float wv = encW[(32+k)*64+lane];
    #pragma unroll
    for(int r=0;r<8;r++) acc[r] += IN[wid][r*16+k]*wv;
  }
  #pragma unroll
  for(int r=0;r<8;r++){
    enc[(base+r)*64+lane] = acc[r];
    E[wid][r*64+lane] = acc[r];
  }
  float h[8];
  #pragma unroll
  for(int r=0;r<8;r++) h[r] = gatb[lane];
  for(int k=0;k<64;k++){
    float wv = gatW[k*64+lane];
    #pragma unroll
    for(int r=0;r<8;r++) h[r] += E[wid][r*64+k]*wv;
  }
  float gal = gata[lane];
  #pragma unroll
  for(int r=0;r<8;r++){
    float hv = tanhf(h[r]);
    HH[(base+r)*64+lane] = hv;
    float s = wsum64(hv*gal);
    if(lane==0) sHH[base+r] = s;
  }
  // ---- folded init (block 0 only) ----
  if(blockIdx.x == 0){
    if(threadIdx.x < 8) out[threadIdx.x] = 0.f;
    float gb0 = grub[lane], gb1 = grub[64+lane], gb2 = grub[128+lane];
    float z1 = sigm(gb0);
    float s1m = (1.f - z1)*tanhf(gb2);
    if(wid==0){
      C[lane] = s1m;
      float a1 = gatb[lane];
      for(int k=0;k<64;k++) a1 += __shfl(s1m,k,64)*gatW[k*64+lane];
      float h2m = tanhf(a1);
      C[64+lane] = h2m;
      float s = wsum64(h2m*gata[lane]);
      if(lane==0) C[128] = s;
    } else {
      int j = wid-1;
      float a2 = 0.f;
      for(int k=0;k<64;k++) a2 += __shfl(s1m,k,64)*gruWh[k*192+64*j+lane];
      hmL[j][lane] = a2;
    }
    __syncthreads();
    if(wid==0){
      float z2 = sigm(gb0 + hmL[0][lane]);
      float r2 = sigm(gb1 + hmL[1][lane]);
      float c2 = tanhf(gb2 + r2*hmL[2][lane]);
      float s2m = z2*s1m + (1.f-z2)*c2;
      C[384+lane] = s2m;
      int hh = lane & 31;
      float a3 = 0.f;
      for(int k=0;k<64;k++) a3 += __shfl(s2m,k,64)*dW1[k*32+hh];
      float t = tanhf(a3 + db1[hh]);
      float p = (lane < 32) ? t*dW2[hh] : 0.f;
      p = wsum64(p);
      if(lane==0) C[448] = p + db2[0];
    }
  }
}

// Edge-parallel GAT aggregation for one row.
__device__ __forceinline__ float gat_agg(
    int row, int bofs, int nn, float hmask, float smask,
    const float* __restrict__ HH, const float* __restrict__ sHH,
    const int* __restrict__ adj)
{
  int ed = threadIdx.x & 15;
  int a16 = adj[row*16 + ed];
  bool m16 = (a16 == nn);
  float sraw = m16 ? smask : sHH[bofs + a16];
  float mx = gmax16(sraw);
  float e = expf(sraw - mx);
  float den = gsum16(e);
  float p = e/den;
  float hr[16];
  #pragma unroll
  for(int d=0; d<16; d++){
    int a_d = __shfl(a16, d, 16);
    hr[d] = (a_d == nn) ? hmask : HH[(bofs + a_d)*64 + (threadIdx.x & 63)];
  }
  float agg = 0.f;
  #pragma unroll
  for(int d=0; d<16; d++){
    float w = __shfl(p, d, 16);
    agg += w*hr[d];
  }
  return agg;
}

// ---------------- K_layer1: GAT1 agg + GRU1 + H2/sH2. 8 rows/wave, Wh staged in LDS ----------------
__global__ void __launch_bounds__(256,2)
k_layer1(const float* __restrict__ enc, const float* __restrict__ HH1,
         const float* __restrict__ sHH1,
         const float* __restrict__ gatW, const float* __restrict__ gatb,
         const float* __restrict__ gata,
         const float* __restrict__ gruWx, const float* __restrict__ gruWh,
         const float* __restrict__ grub,
         const int* __restrict__ adj, const int* __restrict__ num_nodes,
         float* __restrict__ S1, float* __restrict__ HH2,
         float* __restrict__ sHH2)
{
  __shared__ float WhL[12288];    // 48 KB
  __shared__ float LXE[4][1024];  // 16 KB interleaved (x, e)
  __shared__ float LS[4][512];    //  8 KB  -> 72 KB total, 2 blocks/CU
  // stage Wh (overlaps gather phase below)
  {
    const float4* gh = (const float4*)gruWh;
    float4* sh = (float4*)WhL;
    for(int i=threadIdx.x; i<3072; i+=256) sh[i] = gh[i];
  }
  int wid = threadIdx.x>>6, lane = threadIdx.x & 63;
  int base = xcd_base8(blockIdx.x, wid);
  int b = base >> 11;
  int bofs = b << 11;
  int nn = num_nodes[b];
  float tb = tanhf(gatb[lane]);
  float gal = gata[lane];
  float cs = wsum64(tb*gal);
  float e[8];
  #pragma unroll
  for(int r=0;r<8;r++){
    int row = base+r;
    float agg = gat_agg(row, bofs, nn, tb, cs - BIGC, HH1, sHH1, adj);
    e[r] = enc[row*64+lane];
    LXE[wid][(r*64+lane)*2]   = agg + e[r];
    LXE[wid][(r*64+lane)*2+1] = e[r];
  }
  __syncthreads();   // Wh staged + LXE written
  const float2* LXE2 = (const float2*)&LXE[wid][0];
  float ax[8][3], ah[8][3];
  #pragma unroll
  for(int r=0;r<8;r++)
    #pragma unroll
    for(int j=0;j<3;j++){ ax[r][j]=0.f; ah[r][j]=0.f; }
  for(int k=0;k<64;k++){
    float wx0 = gruWx[k*192+lane];
    float wx1 = gruWx[k*192+64+lane];
    float wx2 = gruWx[k*192+128+lane];
    float wh0 = WhL[k*192+lane];
    float wh1 = WhL[k*192+64+lane];
    float wh2 = WhL[k*192+128+lane];
    #pragma unroll
    for(int r=0;r<8;r++){
      float2 xe = LXE2[r*64+k];
      ax[r][0] += xe.x*wx0; ax[r][1] += xe.x*wx1; ax[r][2] += xe.x*wx2;
      ah[r][0] += xe.y*wh0; ah[r][1] += xe.y*wh1; ah[r][2] += xe.y*wh2;
    }
  }
  float gb0 = grub[lane], gb1 = grub[64+lane], gb2 = grub[128+lane];
  #pragma unroll
  for(int r=0;r<8;r++){
    float z = sigm(ax[r][0]+gb0+ah[r][0]);
    float rr = sigm(ax[r][1]+gb1+ah[r][1]);
    float c = tanhf(ax[r][2]+gb2+rr*ah[r][2]);
    float s1 = z*e[r] + (1.f-z)*c;
    S1[(base+r)*64+lane] = s1;
    LS[wid][r*64+lane] = s1;
  }
  float h[8];
  #pragma unroll
  for(int r=0;r<8;r++) h[r] = gatb[lane];
  for(int k=0;k<64;k++){
    float wv = gatW[k*64+lane];
    #pragma unroll
    for(int r=0;r<8;r++) h[r] += LS[wid][r*64+k]*wv;
  }
  #pragma unroll
  for(int r=0;r<8;r++){
    float hv = tanhf(h[r]);
    HH2[(base+r)*64+lane] = hv;
    float s = wsum64(hv*gal);
    if(lane==0) sHH2[base+r] = s;
  }
}

// ---------------- K_layer2: GAT2 agg + GRU2 + decoder. 8 rows/wave, Wh staged in LDS ----------------
__global__ void __launch_bounds__(256,2)
k_layer2(const float* __restrict__ enc, const float* __restrict__ HH2,
         const float* __restrict__ sHH2, const float* __restrict__ C,
         const float* __restrict__ gata,
         const float* __restrict__ gruWx, const float* __restrict__ gruWh,
         const float* __restrict__ grub,
         const float* __restrict__ dW1, const float* __restrict__ db1,
         const float* __restrict__ dW2, const float* __restrict__ db2,
         const int* __restrict__ adj, const int* __restrict__ num_nodes,
         const float* __restrict__ S1,
         float* __restrict__ S2, float* __restrict__ nwn)
{
  __shared__ float WhL[12288];    // 48 KB
  __shared__ float LXS[4][1024];  // 16 KB interleaved (x, s1)
  __shared__ float LS2[4][512];   //  8 KB  -> 72 KB total
  {
    const float4* gh = (const float4*)gruWh;
    float4* sh = (float4*)WhL;
    for(int i=threadIdx.x; i<3072; i+=256) sh[i] = gh[i];
  }
  int wid = threadIdx.x>>6, lane = threadIdx.x & 63;
  int base = xcd_base8(blockIdx.x, wid);
  int b = base >> 11;
  int bofs = b << 11;
  int nn = num_nodes[b];
  float h2m = C[64+lane];
  float sh2m = C[128];
  float s1v[8];
  #pragma unroll
  for(int r=0;r<8;r++){
    int row = base+r;
    float agg = gat_agg(row, bofs, nn, h2m, sh2m - BIGC, HH2, sHH2, adj);
    float x = agg + enc[row*64+lane];
    s1v[r] = S1[row*64+lane];
    LXS[wid][(r*64+lane)*2]   = x;
    LXS[wid][(r*64+lane)*2+1] = s1v[r];
  }
  __syncthreads();
  const float2* LXS2 = (const float2*)&LXS[wid][0];
  float ax[8][3], am[8][3];
  #pragma unroll
  for(int r=0;r<8;r++)
    #pragma unroll
    for(int j=0;j<3;j++){ ax[r][j]=0.f; am[r][j]=0.f; }
  for(int k=0;k<64;k++){
    float wx0 = gruWx[k*192+lane];
    float wx1 = gruWx[k*192+64+lane];
    float wx2 = gruWx[k*192+128+lane];
    float wh0 = WhL[k*192+lane];
    float wh1 = WhL[k*192+64+lane];
    float wh2 = WhL[k*192+128+lane];
    #pragma unroll
    for(int r=0;r<8;r++){
      float2 xs = LXS2[r*64+k];
      ax[r][0] += xs.x*wx0; ax[r][1] += xs.x*wx1; ax[r][2] += xs.x*wx2;
      am[r][0] += xs.y*wh0; am[r][1] += xs.y*wh1; am[r][2] += xs.y*wh2;
    }
  }
  float gb0 = grub[lane], gb1 = grub[64+lane], gb2 = grub[128+lane];
  #pragma unroll
  for(int r=0;r<8;r++){
    float z = sigm(ax[r][0]+gb0+am[r][0]);
    float rr = sigm(ax[r][1]+gb1+am[r][1]);
    float c = tanhf(ax[r][2]+gb2+rr*am[r][2]);
    float s2 = z*s1v[r] + (1.f-z)*c;
    S2[(base+r)*64+lane] = s2;
    LS2[wid][r*64+lane] = s2;
  }
  int h = lane & 31;
  float accd[8];
  #pragma unroll
  for(int r=0;r<8;r++) accd[r]=0.f;
  for(int k=0;k<64;k++){
    float wv = dW1[k*32+h];
    #pragma unroll
    for(int r=0;r<8;r++) accd[r] += LS2[wid][r*64+k]*wv;
  }
  float b1 = db1[h], w2 = dW2[h], b2 = db2[0];
  #pragma unroll
  for(int r=0;r<8;r++){
    float t = tanhf(accd[r] + b1);
    float p = (lane<32) ? t*w2 : 0.f;
    p = wsum64(p);
    if(lane==0) nwn[base+r] = p + b2;
  }
}

// ---------------- K_tail: node_states gather + dual head + nw gather. 8 rows/wave ----------------
__global__ void __launch_bounds__(256,2)
k_tail(const float* __restrict__ S2, const float* __restrict__ nwn,
       const float* __restrict__ C,
       const float* __restrict__ uW1, const float* __restrict__ ub1,
       const float* __restrict__ uW2, const float* __restrict__ ub2,
       const int* __restrict__ adj, const int* __restrict__ num_nodes,
       float* __restrict__ nw, float* __restrict__ dv)
{
  __shared__ float LN[4][512];
  int wid = threadIdx.x>>6, lane = threadIdx.x&63;
  int base = xcd_base8(blockIdx.x, wid);
  int b = base>>11;
  int bofs = b<<11;
  int nn = num_nodes[b];
  float s2m = C[384+lane];
  float nwm = C[448];
  #pragma unroll
  for(int r=0;r<8;r++){
    int row = base+r;
    int ed = lane & 15;
    int a16 = adj[row*16 + ed];
    float hr[16];
    #pragma unroll
    for(int d=0;d<16;d++){
      int a_d = __shfl(a16, d, 16);
      hr[d] = (a_d==nn) ? s2m : S2[(bofs+a_d)*64+lane];
    }
    float ns = 0.f;
    #pragma unroll
    for(int d=0;d<16;d++) ns += hr[d];
    LN[wid][r*64+lane] = ns;
    if(lane < 16){
      bool m = (a16==nn);
      nw[row*16+lane] = m ? nwm : nwn[bofs+a16];
    }
  }
  int h = lane & 31;
  float acc[8];
  #pragma unroll
  for(int r=0;r<8;r++) acc[r]=0.f;
  for(int k=0;k<64;k++){
    float wv = uW1[k*32+h];
    #pragma unroll
    for(int r=0;r<8;r++) acc[r] += LN[wid][r*64+k]*wv;
  }
  float b1 = ub1[h], w2 = uW2[h], b2 = ub2[0];
  #pragma unroll
  for(int r=0;r<8;r++){
    float t = tanhf(acc[r] + b1);
    float p = (lane<32) ? t*w2 : 0.f;
    p = wsum64(p);
    if(lane==0) dv[base+r] = p + b2;
  }
}

// ---------------- K5: incoming gather + softmax(in). edge-parallel ----------------
__global__ void k_attn_in(const float* __restrict__ nw, const int* __restrict__ in_idx,
                          const int* __restrict__ inv_adj, const int* __restrict__ num_nodes,
                          float* __restrict__ attn_in)
{
  int b = blockIdx.x & 7, slot = blockIdx.x >> 3;
  int e = b*32768 + slot*256 + threadIdx.x;
  int nn = num_nodes[b];
  float w = nw[b*32768 + in_idx[e]];
  bool im = (inv_adj[e]==nn);
  float sc = w - (im ? BIGC : 0.f);
  float mx = gmax16(sc);
  float ex = expf(sc-mx);
  float den = gsum16(ex);
  attn_in[e] = ex/den;
}

// ---------------- K6: rev gather + softmax -> normalized. edge-parallel ----------------
__global__ void k_norm(const float* __restrict__ attn_in, const int* __restrict__ rev_idx,
                       const int* __restrict__ adj, const int* __restrict__ num_nodes,
                       float* __restrict__ normalized)
{
  int b = blockIdx.x & 7, slot = blockIdx.x >> 3;
  int e = b*32768 + slot*256 + threadIdx.x;
  int nn = num_nodes[b];
  float g = attn_in[b*32768 + rev_idx[e]];
  bool m = (adj[e]==nn);
  float sc = g - (m ? BIGC : 0.f);
  float mx = gmax16(sc);
  float ex = expf(sc-mx);
  float den = gsum16(ex);
  normalized[e] = ex/den;
}

// ---------------- K_prep_dual: mcf tables + qv AND dual iterations, one launch ----------------
__global__ void k_prep_dual(const float* __restrict__ normalized, const int* __restrict__ in_idx,
                            const int* __restrict__ inv_adj, const int* __restrict__ num_nodes,
                            const float* __restrict__ dual_vars, const float* __restrict__ demands,
                            const int* __restrict__ adj,
                            float* __restrict__ wq, int* __restrict__ srcq,
                            float* __restrict__ qv, float* __restrict__ out)
{
  int b = blockIdx.x & 7, slot = blockIdx.x >> 3;
  int e = b*32768 + slot*256 + threadIdx.x;
  int v = e >> 4;
  int nn = num_nodes[b];
  // --- mcf prep part ---
  int ii = in_idx[e];
  bool im = (inv_adj[e]==nn);
  wq[e] = im ? 0.f : normalized[b*32768 + ii];
  srcq[e] = ii >> 4;
  float nv = normalized[e];
  float qq = gsum16(nv*nv);
  if((e & 15) == 0) qv[v] = qq;
  // --- dual part ---
  float dvv = dual_vars[v];
  int a = adj[e];
  bool m = (a==nn);
  float dvn = dual_vars[(b<<11)+a];
  float dd = m ? (-dvv) : dvn;
  float valid = m ? 0.f : 1.f;
  float f=0.f, acc=0.f;
  #pragma unroll
  for(int it=0; it<10; ++it){
    float grad = 2.f*f + dd;
    acc = 0.9f*acc + 0.01f*grad;
    f = fmaxf(f-acc, 0.f)*valid;
  }
  float contrib = -(f*f + dd*f);
  if((e & 15) == 0) contrib += dvv * demands[v];
  float s = wsum64(contrib);
  __shared__ float red[4];
  int wid = threadIdx.x>>6, lane = threadIdx.x&63;
  if(lane==0) red[wid]=s;
  __syncthreads();
  if(threadIdx.x==0) atomicAdd(out+b, red[0]+red[1]+red[2]+red[3]);
}

// ---------------- K7: MCF iterations via float4/int4 tables + LDS state ----------------
__global__ void __launch_bounds__(1024,1)
k_mcf(const float* __restrict__ wq, const int* __restrict__ srcq,
      const float* __restrict__ qv, const float* __restrict__ demands,
      float* __restrict__ out)
{
  __shared__ float T[2][2048];
  int b = blockIdx.x; int tid = threadIdx.x;  // 1024 threads, 2 nodes/thread
  const float4* w4 = (const float4*)(wq + b*32768);
  const int4*   s4 = (const int4*)(srcq + b*32768);
  float sup[2], q[2];
  float4 wr[2][4]; int4 sr[2][4];
  #pragma unroll
  for(int s=0;s<2;s++){
    int vi = tid + s*1024;
    sup[s] = fmaxf(-demands[b*2048+vi], 0.f);
    q[s] = qv[b*2048+vi];
    #pragma unroll
    for(int g=0;g<4;g++){ wr[s][g] = w4[vi*4+g]; sr[s][g] = s4[vi*4+g]; }
    T[0][vi] = sup[s];
  }
  __syncthreads();
  int cur = 0;
  for(int it=0; it<10; ++it){
    float nt[2];
    #pragma unroll
    for(int s=0;s<2;s++){
      float acc = sup[s];
      #pragma unroll
      for(int g=0;g<4;g++){
        float4 w = wr[s][g]; int4 sc = sr[s][g];
        acc += w.x*T[cur][sc.x] + w.y*T[cur][sc.y] + w.z*T[cur][sc.z] + w.w*T[cur][sc.w];
      }
      nt[s] = acc;
    }
    #pragma unroll
    for(int s=0;s<2;s++) T[cur^1][tid+s*1024] = nt[s];
    __syncthreads();
    cur ^= 1;
  }
  float fc = q[0]*T[cur][tid]*T[cur][tid] + q[1]*T[cur][tid+1024]*T[cur][tid+1024];
  fc = wsum64(fc);
  __shared__ float red[16];
  int wid = tid>>6, lane = tid&63;
  if(lane==0) red[wid]=fc;
  __syncthreads();
  if(tid==0){
    float s=0.f;
    for(int i=0;i<16;i++) s+=red[i];
    atomicAdd(out+b, s);
  }
}

extern "C" void kernel_launch(void* const* d_in, const int* in_sizes, int n_in,
                              void* d_out, int out_size, void* d_ws, size_t ws_size,
                              hipStream_t stream)
{
  const float* feat = (const float*)d_in[0];
  const float* dem  = (const float*)d_in[1];
  const float* emb  = (const float*)d_in[2];
  const float* encW = (const float*)d_in[3];
  const float* encb = (const float*)d_in[4];
  const float* gatW = (const float*)d_in[5];
  const float* gatb = (const float*)d_in[6];
  const float* gata = (const float*)d_in[7];
  const float* gruWx= (const float*)d_in[8];
  const float* gruWh= (const float*)d_in[9];
  const float* grub = (const float*)d_in[10];
  const float* dW1  = (const float*)d_in[11];
  const float* db1  = (const float*)d_in[12];
  const float* dW2  = (const float*)d_in[13];
  const float* db2  = (const float*)d_in[14];
  const float* uW1  = (const float*)d_in[15];
  const float* ub1  = (const float*)d_in[16];
  const float* uW2  = (const float*)d_in[17];
  const float* ub2  = (const float*)d_in[18];
  const int* adj    = (const int*)d_in[19];
  const int* invadj = (const int*)d_in[20];
  const int* inidx  = (const int*)d_in[21];
  const int* revidx = (const int*)d_in[22];
  const int* nnodes = (const int*)d_in[23];
  float* out = (float*)d_out;

  float* ws = (float*)d_ws;
  size_t off=0;
  float* enc  = ws+off; off += (size_t)16384*64;
  float* HH1  = ws+off; off += (size_t)16384*64;
  float* sHH1 = ws+off; off += (size_t)16384;
  float* S1   = ws+off; off += (size_t)16384*64;
  float* HH2  = ws+off; off += (size_t)16384*64;
  float* sHH2 = ws+off; off += (size_t)16384;
  float* S2   = ws+off; off += (size_t)16384*64;
  float* nwn  = ws+off; off += (size_t)16384;
  float* C    = ws+off; off += (size_t)512;
  float* nwb  = ws+off; off += (size_t)16384*16;
  float* attn = ws+off; off += (size_t)16384*16;
  float* nrm  = ws+off; off += (size_t)16384*16;
  float* dv   = ws+off; off += (size_t)16384;
  float* P    = ws+off; off += (size_t)2048*64;
  float* wq   = ws+off; off += (size_t)16384*16;
  float* srcq = ws+off; off += (size_t)16384*16;
  float* qv   = ws+off; off += (size_t)16384;
  (void)ws_size; (void)in_sizes; (void)n_in; (void)out_size;

  k_emb<<<64,256,0,stream>>>(emb,encW,encb, P);
  k_enc<<<512,256,0,stream>>>(feat,P,encW,gatW,gatb,gata,gruWh,grub,dW1,db1,dW2,db2, enc,HH1,sHH1,out,C);
  k_layer1<<<512,256,0,stream>>>(enc,HH1,sHH1,gatW,gatb,gata,gruWx,gruWh,grub,adj,nnodes, S1,HH2,sHH2);
  k_layer2<<<512,256,0,stream>>>(enc,HH2,sHH2,C,gata,gruWx,gruWh,grub,dW1,db1,dW2,db2,adj,nnodes,S1, S2,nwn);
  k_tail<<<512,256,0,stream>>>(S2,nwn,C,uW1,ub1,uW2,ub2,adj,nnodes, nwb,dv);
  k_attn_in<<<1024,256,0,stream>>>(nwb,inidx,invadj,nnodes, attn);
  k_norm<<<1024,256,0,stream>>>(attn,revidx,adj,nnodes, nrm);
  k_prep_dual<<<1024,256,0,stream>>>(nrm,inidx,invadj,nnodes,dv,dem,adj, wq,(int*)srcq,qv,out);
  k_mcf<<<8,1024,0,stream>>>(wq,(const int*)srcq,qv,dem, out);
}

// Round 15
// 323.996 us; speedup vs baseline: 1.0131x; 1.0131x over previous
//
#include <hip/hip_runtime.h>
#include <math.h>

#define VV 2048
#define BIGC 1e9f

__device__ __forceinline__ float wsum64(float v){
  v += __shfl_xor(v, 1, 64);
  v += __shfl_xor(v, 2, 64);
  v += __shfl_xor(v, 4, 64);
  v += __shfl_xor(v, 8, 64);
  v += __shfl_xor(v, 16, 64);
  v += __shfl_xor(v, 32, 64);
  return v;
}
__device__ __forceinline__ float gmax16(float v){
  v = fmaxf(v, __shfl_xor(v, 1, 16));
  v = fmaxf(v, __shfl_xor(v, 2, 16));
  v = fmaxf(v, __shfl_xor(v, 4, 16));
  v = fmaxf(v, __shfl_xor(v, 8, 16));
  return v;
}
__device__ __forceinline__ float gsum16(float v){
  v += __shfl_xor(v, 1, 16);
  v += __shfl_xor(v, 2, 16);
  v += __shfl_xor(v, 4, 16);
  v += __shfl_xor(v, 8, 16);
  return v;
}
__device__ __forceinline__ float sigm(float x){ return 1.f/(1.f+expf(-x)); }

// 8 rows/wave mapping: batch = blk&7 (XCD round-robin), slot = blk>>3 in [0,64)
__device__ __forceinline__ int xcd_base8(int blk, int wid){
  int b = blk & 7, slot = blk >> 3;
  return b*VV + slot*32 + wid*8;
}
// 4 rows/wave mapping: slot = blk>>3 in [0,128)
__device__ __forceinline__ int xcd_base4(int blk, int wid){
  int b = blk & 7, slot = blk >> 3;
  return b*VV + slot*16 + wid*4;
}

// ---------------- K_emb: batch-independent encoder part P[u] = emb_c[u]@encW[:32] + encb ----------------
__global__ void __launch_bounds__(256,2)
k_emb(const float* __restrict__ emb, const float* __restrict__ encW,
      const float* __restrict__ encb, float* __restrict__ P)
{
  __shared__ float EC[4][256];
  int wid = threadIdx.x>>6, lane = threadIdx.x&63;
  int base = blockIdx.x*32 + wid*8;
  #pragma unroll
  for(int r=0;r<8;r++){
    int u = base+r;
    float ev = (lane < 32) ? emb[u*32 + lane] : 0.f;
    float ss = wsum64(ev*ev);
    float sc = (ss > 1.f) ? 1.f/sqrtf(ss) : 1.f;
    if(lane < 32) EC[wid][r*32+lane] = ev*sc;
  }
  float acc[8];
  #pragma unroll
  for(int r=0;r<8;r++) acc[r] = encb[lane];
  for(int k=0;k<32;k++){
    float wv = encW[k*64+lane];
    #pragma unroll
    for(int r=0;r<8;r++) acc[r] += EC[wid][r*32+k]*wv;
  }
  #pragma unroll
  for(int r=0;r<8;r++) P[(base+r)*64+lane] = acc[r];
}

// ---------------- K_enc: per-node encoder (feat part + P) + H1/sH1 (+ folded init in block 0) ----------------
// C layout: [0:64) s1m | [64:128) h2m | [128] sh2m | [384:448) s2m | [448] nwm
__global__ void __launch_bounds__(256,2)
k_enc(const float* __restrict__ feat, const float* __restrict__ P,
      const float* __restrict__ encW,
      const float* __restrict__ gatW, const float* __restrict__ gatb,
      const float* __restrict__ gata,
      const float* __restrict__ gruWh, const float* __restrict__ grub,
      const float* __restrict__ dW1, const float* __restrict__ db1,
      const float* __restrict__ dW2, const float* __restrict__ db2,
      float* __restrict__ enc, float* __restrict__ HH,
      float* __restrict__ sHH, float* __restrict__ out, float* __restrict__ C)
{
  __shared__ float IN[4][128];
  __shared__ float E[4][512];
  __shared__ float hmL[3][64];
  int wid = threadIdx.x >> 6, lane = threadIdx.x & 63;
  int base = xcd_base8(blockIdx.x, wid);
  #pragma unroll
  for(int r=0;r<8;r++){
    int row = base+r;
    if(lane < 16) IN[wid][r*16+lane] = feat[row*16 + lane];
  }
  float acc[8];
  #pragma unroll
  for(int r=0;r<8;r++){
    int u = (base+r) & (VV-1);
    acc[r] = P[u*64+lane];
  }
  for(int k=0;k<16;k++){
    float wv = encW[(32+k)*64+lane];
    #pragma unroll
    for(int r=0;r<8;r++) acc[r] += IN[wid][r*16+k]*wv;
  }
  #pragma unroll
  for(int r=0;r<8;r++){
    enc[(base+r)*64+lane] = acc[r];
    E[wid][r*64+lane] = acc[r];
  }
  float h[8];
  #pragma unroll
  for(int r=0;r<8;r++) h[r] = gatb[lane];
  for(int k=0;k<64;k++){
    float wv = gatW[k*64+lane];
    #pragma unroll
    for(int r=0;r<8;r++) h[r] += E[wid][r*64+k]*wv;
  }
  float gal = gata[lane];
  #pragma unroll
  for(int r=0;r<8;r++){
    float hv = tanhf(h[r]);
    HH[(base+r)*64+lane] = hv;
    float s = wsum64(hv*gal);
    if(lane==0) sHH[base+r] = s;
  }
  // ---- folded init (block 0 only) ----
  if(blockIdx.x == 0){
    if(threadIdx.x < 8) out[threadIdx.x] = 0.f;
    float gb0 = grub[lane], gb1 = grub[64+lane], gb2 = grub[128+lane];
    float z1 = sigm(gb0);
    float s1m = (1.f - z1)*tanhf(gb2);
    if(wid==0){
      C[lane] = s1m;
      float a1 = gatb[lane];
      for(int k=0;k<64;k++) a1 += __shfl(s1m,k,64)*gatW[k*64+lane];
      float h2m = tanhf(a1);
      C[64+lane] = h2m;
      float s = wsum64(h2m*gata[lane]);
      if(lane==0) C[128] = s;
    } else {
      int j = wid-1;
      float a2 = 0.f;
      for(int k=0;k<64;k++) a2 += __shfl(s1m,k,64)*gruWh[k*192+64*j+lane];
      hmL[j][lane] = a2;
    }
    __syncthreads();
    if(wid==0){
      float z2 = sigm(gb0 + hmL[0][lane]);
      float r2 = sigm(gb1 + hmL[1][lane]);
      float c2 = tanhf(gb2 + r2*hmL[2][lane]);
      float s2m = z2*s1m + (1.f-z2)*c2;
      C[384+lane] = s2m;
      int hh = lane & 31;
      float a3 = 0.f;
      for(int k=0;k<64;k++) a3 += __shfl(s2m,k,64)*dW1[k*32+hh];
      float t = tanhf(a3 + db1[hh]);
      float p = (lane < 32) ? t*dW2[hh] : 0.f;
      p = wsum64(p);
      if(lane==0) C[448] = p + db2[0];
    }
  }
}

// Edge-parallel GAT aggregation for one row.
__device__ __forceinline__ float gat_agg(
    int row, int bofs, int nn, float hmask, float smask,
    const float* __restrict__ HH, const float* __restrict__ sHH,
    const int* __restrict__ adj)
{
  int ed = threadIdx.x & 15;
  int a16 = adj[row*16 + ed];
  bool m16 = (a16 == nn);
  float sraw = m16 ? smask : sHH[bofs + a16];
  float mx = gmax16(sraw);
  float e = expf(sraw - mx);
  float den = gsum16(e);
  float p = e/den;
  float hr[16];
  #pragma unroll
  for(int d=0; d<16; d++){
    int a_d = __shfl(a16, d, 16);
    hr[d] = (a_d == nn) ? hmask : HH[(bofs + a_d)*64 + (threadIdx.x & 63)];
  }
  float agg = 0.f;
  #pragma unroll
  for(int d=0; d<16; d++){
    float w = __shfl(p, d, 16);
    agg += w*hr[d];
  }
  return agg;
}

// ---------------- K_layer1: A/B variant — 4 rows/wave, bounds(256,3) ----------------
__global__ void __launch_bounds__(256,3)
k_layer1(const float* __restrict__ enc, const float* __restrict__ HH1,
         const float* __restrict__ sHH1,
         const float* __restrict__ gatW, const float* __restrict__ gatb,
         const float* __restrict__ gata,
         const float* __restrict__ gruWx, const float* __restrict__ gruWh,
         const float* __restrict__ grub,
         const int* __restrict__ adj, const int* __restrict__ num_nodes,
         float* __restrict__ S1, float* __restrict__ HH2,
         float* __restrict__ sHH2)
{
  __shared__ float LXE[4][512];   // interleaved (x, e): 4 rows x 64 x 2
  __shared__ float LS[4][256];
  int wid = threadIdx.x>>6, lane = threadIdx.x & 63;
  int base = xcd_base4(blockIdx.x, wid);
  int b = base >> 11;
  int bofs = b << 11;
  int nn = num_nodes[b];
  float tb = tanhf(gatb[lane]);
  float gal = gata[lane];
  float cs = wsum64(tb*gal);
  float e[4];
  #pragma unroll
  for(int r=0;r<4;r++){
    int row = base+r;
    float agg = gat_agg(row, bofs, nn, tb, cs - BIGC, HH1, sHH1, adj);
    e[r] = enc[row*64+lane];
    LXE[wid][(r*64+lane)*2]   = agg + e[r];
    LXE[wid][(r*64+lane)*2+1] = e[r];
  }
  const float2* LXE2 = (const float2*)&LXE[wid][0];
  float ax[4][3], ah[4][3];
  #pragma unroll
  for(int r=0;r<4;r++)
    #pragma unroll
    for(int j=0;j<3;j++){ ax[r][j]=0.f; ah[r][j]=0.f; }
  for(int k=0;k<64;k++){
    float wx0 = gruWx[k*192+lane];
    float wx1 = gruWx[k*192+64+lane];
    float wx2 = gruWx[k*192+128+lane];
    float wh0 = gruWh[k*192+lane];
    float wh1 = gruWh[k*192+64+lane];
    float wh2 = gruWh[k*192+128+lane];
    #pragma unroll
    for(int r=0;r<4;r++){
      float2 xe = LXE2[r*64+k];
      ax[r][0] += xe.x*wx0; ax[r][1] += xe.x*wx1; ax[r][2] += xe.x*wx2;
      ah[r][0] += xe.y*wh0; ah[r][1] += xe.y*wh1; ah[r][2] += xe.y*wh2;
    }
  }
  float gb0 = grub[lane], gb1 = grub[64+lane], gb2 = grub[128+lane];
  #pragma unroll
  for(int r=0;r<4;r++){
    float z = sigm(ax[r][0]+gb0+ah[r][0]);
    float rr = sigm(ax[r][1]+gb1+ah[r][1]);
    float c = tanhf(ax[r][2]+gb2+rr*ah[r][2]);
    float s1 = z*e[r] + (1.f-z)*c;
    S1[(base+r)*64+lane] = s1;
    LS[wid][r*64+lane] = s1;
  }
  float h[4];
  #pragma unroll
  for(int r=0;r<4;r++) h[r] = gatb[lane];
  for(int k=0;k<64;k++){
    float wv = gatW[k*64+lane];
    #pragma unroll
    for(int r=0;r<4;r++) h[r] += LS[wid][r*64+k]*wv;
  }
  #pragma unroll
  for(int r=0;r<4;r++){
    float hv = tanhf(h[r]);
    HH2[(base+r)*64+lane] = hv;
    float s = wsum64(hv*gal);
    if(lane==0) sHH2[base+r] = s;
  }
}

// ---------------- K_layer2: R11 shape — 8 rows/wave, (x,s1) b64 interleave ----------------
__global__ void __launch_bounds__(256,2)
k_layer2(const float* __restrict__ enc, const float* __restrict__ HH2,
         const float* __restrict__ sHH2, const float* __restrict__ C,
         const float* __restrict__ gata,
         const float* __restrict__ gruWx, const float* __restrict__ gruWh,
         const float* __restrict__ grub,
         const float* __restrict__ dW1, const float* __restrict__ db1,
         const float* __restrict__ dW2, const float* __restrict__ db2,
         const int* __restrict__ adj, const int* __restrict__ num_nodes,
         const float* __restrict__ S1,
         float* __restrict__ S2, float* __restrict__ nwn)
{
  __shared__ float LXS[4][1024];
  __shared__ float LS2[4][512];
  int wid = threadIdx.x>>6, lane = threadIdx.x & 63;
  int base = xcd_base8(blockIdx.x, wid);
  int b = base >> 11;
  int bofs = b << 11;
  int nn = num_nodes[b];
  float h2m = C[64+lane];
  float sh2m = C[128];
  float s1v[8];
  #pragma unroll
  for(int r=0;r<8;r++){
    int row = base+r;
    float agg = gat_agg(row, bofs, nn, h2m, sh2m - BIGC, HH2, sHH2, adj);
    float x = agg + enc[row*64+lane];
    s1v[r] = S1[row*64+lane];
    LXS[wid][(r*64+lane)*2]   = x;
    LXS[wid][(r*64+lane)*2+1] = s1v[r];
  }
  const float2* LXS2 = (const float2*)&LXS[wid][0];
  float ax[8][3], am[8][3];
  #pragma unroll
  for(int r=0;r<8;r++)
    #pragma unroll
    for(int j=0;j<3;j++){ ax[r][j]=0.f; am[r][j]=0.f; }
  for(int k=0;k<64;k++){
    float wx0 = gruWx[k*192+lane];
    float wx1 = gruWx[k*192+64+lane];
    float wx2 = gruWx[k*192+128+lane];
    float wh0 = gruWh[k*192+lane];
    float wh1 = gruWh[k*192+64+lane];
    float wh2 = gruWh[k*192+128+lane];
    #pragma unroll
    for(int r=0;r<8;r++){
      float2 xs = LXS2[r*64+k];
      ax[r][0] += xs.x*wx0; ax[r][1] += xs.x*wx1; ax[r][2] += xs.x*wx2;
      am[r][0] += xs.y*wh0; am[r][1] += xs.y*wh1; am[r][2] += xs.y*wh2;
    }
  }
  float gb0 = grub[lane], gb1 = grub[64+lane], gb2 = grub[128+lane];
  #pragma unroll
  for(int r=0;r<8;r++){
    float z = sigm(ax[r][0]+gb0+am[r][0]);
    float rr = sigm(ax[r][1]+gb1+am[r][1]);
    float c = tanhf(ax[r][2]+gb2+rr*am[r][2]);
    float s2 = z*s1v[r] + (1.f-z)*c;
    S2[(base+r)*64+lane] = s2;
    LS2[wid][r*64+lane] = s2;
  }
  int h = lane & 31;
  float accd[8];
  #pragma unroll
  for(int r=0;r<8;r++) accd[r]=0.f;
  for(int k=0;k<64;k++){
    float wv = dW1[k*32+h];
    #pragma unroll
    for(int r=0;r<8;r++) accd[r] += LS2[wid][r*64+k]*wv;
  }
  float b1 = db1[h], w2 = dW2[h], b2 = db2[0];
  #pragma unroll
  for(int r=0;r<8;r++){
    float t = tanhf(accd[r] + b1);
    float p = (lane<32) ? t*w2 : 0.f;
    p = wsum64(p);
    if(lane==0) nwn[base+r] = p + b2;
  }
}

// ---------------- K_tail: node_states gather + dual head + nw gather. 8 rows/wave ----------------
__global__ void __launch_bounds__(256,2)
k_tail(const float* __restrict__ S2, const float* __restrict__ nwn,
       const float* __restrict__ C,
       const float* __restrict__ uW1, const float* __restrict__ ub1,
       const float* __restrict__ uW2, const float* __restrict__ ub2,
       const int* __restrict__ adj, const int* __restrict__ num_nodes,
       float* __restrict__ nw, float* __restrict__ dv)
{
  __shared__ float LN[4][512];
  int wid = threadIdx.x>>6, lane = threadIdx.x&63;
  int base = xcd_base8(blockIdx.x, wid);
  int b = base>>11;
  int bofs = b<<11;
  int nn = num_nodes[b];
  float s2m = C[384+lane];
  float nwm = C[448];
  #pragma unroll
  for(int r=0;r<8;r++){
    int row = base+r;
    int ed = lane & 15;
    int a16 = adj[row*16 + ed];
    float hr[16];
    #pragma unroll
    for(int d=0;d<16;d++){
      int a_d = __shfl(a16, d, 16);
      hr[d] = (a_d==nn) ? s2m : S2[(bofs+a_d)*64+lane];
    }
    float ns = 0.f;
    #pragma unroll
    for(int d=0;d<16;d++) ns += hr[d];
    LN[wid][r*64+lane] = ns;
    if(lane < 16){
      bool m = (a16==nn);
      nw[row*16+lane] = m ? nwm : nwn[bofs+a16];
    }
  }
  int h = lane & 31;
  float acc[8];
  #pragma unroll
  for(int r=0;r<8;r++) acc[r]=0.f;
  for(int k=0;k<64;k++){
    float wv = uW1[k*32+h];
    #pragma unroll
    for(int r=0;r<8;r++) acc[r] += LN[wid][r*64+k]*wv;
  }
  float b1 = ub1[h], w2 = uW2[h], b2 = ub2[0];
  #pragma unroll
  for(int r=0;r<8;r++){
    float t = tanhf(acc[r] + b1);
    float p = (lane<32) ? t*w2 : 0.f;
    p = wsum64(p);
    if(lane==0) dv[base+r] = p + b2;
  }
}

// ---------------- K5: incoming gather + softmax(in). edge-parallel ----------------
__global__ void k_attn_in(const float* __restrict__ nw, const int* __restrict__ in_idx,
                          const int* __restrict__ inv_adj, const int* __restrict__ num_nodes,
                          float* __restrict__ attn_in)
{
  int b = blockIdx.x & 7, slot = blockIdx.x >> 3;
  int e = b*32768 + slot*256 + threadIdx.x;
  int nn = num_nodes[b];
  float w = nw[b*32768 + in_idx[e]];
  bool im = (inv_adj[e]==nn);
  float sc = w - (im ? BIGC : 0.f);
  float mx = gmax16(sc);
  float ex = expf(sc-mx);
  float den = gsum16(ex);
  attn_in[e] = ex/den;
}

// ---------------- K6: rev gather + softmax -> normalized. edge-parallel ----------------
__global__ void k_norm(const float* __restrict__ attn_in, const int* __restrict__ rev_idx,
                       const int* __restrict__ adj, const int* __restrict__ num_nodes,
                       float* __restrict__ normalized)
{
  int b = blockIdx.x & 7, slot = blockIdx.x >> 3;
  int e = b*32768 + slot*256 + threadIdx.x;
  int nn = num_nodes[b];
  float g = attn_in[b*32768 + rev_idx[e]];
  bool m = (adj[e]==nn);
  float sc = g - (m ? BIGC : 0.f);
  float mx = gmax16(sc);
  float ex = expf(sc-mx);
  float den = gsum16(ex);
  normalized[e] = ex/den;
}

// ---------------- K_prep_dual: mcf tables + qv AND dual iterations, one launch ----------------
__global__ void k_prep_dual(const float* __restrict__ normalized, const int* __restrict__ in_idx,
                            const int* __restrict__ inv_adj, const int* __restrict__ num_nodes,
                            const float* __restrict__ dual_vars, const float* __restrict__ demands,
                            const int* __restrict__ adj,
                            float* __restrict__ wq, int* __restrict__ srcq,
                            float* __restrict__ qv, float* __restrict__ out)
{
  int b = blockIdx.x & 7, slot = blockIdx.x >> 3;
  int e = b*32768 + slot*256 + threadIdx.x;
  int v = e >> 4;
  int nn = num_nodes[b];
  // --- mcf prep part ---
  int ii = in_idx[e];
  bool im = (inv_adj[e]==nn);
  wq[e] = im ? 0.f : normalized[b*32768 + ii];
  srcq[e] = ii >> 4;
  float nv = normalized[e];
  float qq = gsum16(nv*nv);
  if((e & 15) == 0) qv[v] = qq;
  // --- dual part ---
  float dvv = dual_vars[v];
  int a = adj[e];
  bool m = (a==nn);
  float dvn = dual_vars[(b<<11)+a];
  float dd = m ? (-dvv) : dvn;
  float valid = m ? 0.f : 1.f;
  float f=0.f, acc=0.f;
  #pragma unroll
  for(int it=0; it<10; ++it){
    float grad = 2.f*f + dd;
    acc = 0.9f*acc + 0.01f*grad;
    f = fmaxf(f-acc, 0.f)*valid;
  }
  float contrib = -(f*f + dd*f);
  if((e & 15) == 0) contrib += dvv * demands[v];
  float s = wsum64(contrib);
  __shared__ float red[4];
  int wid = threadIdx.x>>6, lane = threadIdx.x&63;
  if(lane==0) red[wid]=s;
  __syncthreads();
  if(threadIdx.x==0) atomicAdd(out+b, red[0]+red[1]+red[2]+red[3]);
}

// ---------------- K7: MCF iterations via float4/int4 tables + LDS state ----------------
__global__ void __launch_bounds__(1024,1)
k_mcf(const float* __restrict__ wq, const int* __restrict__ srcq,
      const float* __restrict__ qv, const float* __restrict__ demands,
      float* __restrict__ out)
{
  __shared__ float T[2][2048];
  int b = blockIdx.x; int tid = threadIdx.x;  // 1024 threads, 2 nodes/thread
  const float4* w4 = (const float4*)(wq + b*32768);
  const int4*   s4 = (const int4*)(srcq + b*32768);
  float sup[2], q[2];
  float4 wr[2][4]; int4 sr[2][4];
  #pragma unroll
  for(int s=0;s<2;s++){
    int vi = tid + s*1024;
    sup[s] = fmaxf(-demands[b*2048+vi], 0.f);
    q[s] = qv[b*2048+vi];
    #pragma unroll
    for(int g=0;g<4;g++){ wr[s][g] = w4[vi*4+g]; sr[s][g] = s4[vi*4+g]; }
    T[0][vi] = sup[s];
  }
  __syncthreads();
  int cur = 0;
  for(int it=0; it<10; ++it){
    float nt[2];
    #pragma unroll
    for(int s=0;s<2;s++){
      float acc = sup[s];
      #pragma unroll
      for(int g=0;g<4;g++){
        float4 w = wr[s][g]; int4 sc = sr[s][g];
        acc += w.x*T[cur][sc.x] + w.y*T[cur][sc.y] + w.z*T[cur][sc.z] + w.w*T[cur][sc.w];
      }
      nt[s] = acc;
    }
    #pragma unroll
    for(int s=0;s<2;s++) T[cur^1][tid+s*1024] = nt[s];
    __syncthreads();
    cur ^= 1;
  }
  float fc = q[0]*T[cur][tid]*T[cur][tid] + q[1]*T[cur][tid+1024]*T[cur][tid+1024];
  fc = wsum64(fc);
  __shared__ float red[16];
  int wid = tid>>6, lane = tid&63;
  if(lane==0) red[wid]=fc;
  __syncthreads();
  if(tid==0){
    float s=0.f;
    for(int i=0;i<16;i++) s+=red[i];
    atomicAdd(out+b, s);
  }
}

extern "C" void kernel_launch(void* const* d_in, const int* in_sizes, int n_in,
                              void* d_out, int out_size, void* d_ws, size_t ws_size,
                              hipStream_t stream)
{
  const float* feat = (const float*)d_in[0];
  const float* dem  = (const float*)d_in[1];
  const float* emb  = (const float*)d_in[2];
  const float* encW = (const float*)d_in[3];
  const float* encb = (const float*)d_in[4];
  const float* gatW = (const float*)d_in[5];
  const float* gatb = (const float*)d_in[6];
  const float* gata = (const float*)d_in[7];
  const float* gruWx= (const float*)d_in[8];
  const float* gruWh= (const float*)d_in[9];
  const float* grub = (const float*)d_in[10];
  const float* dW1  = (const float*)d_in[11];
  const float* db1  = (const float*)d_in[12];
  const float* dW2  = (const float*)d_in[13];
  const float* db2  = (const float*)d_in[14];
  const float* uW1  = (const float*)d_in[15];
  const float* ub1  = (const float*)d_in[16];
  const float* uW2  = (const float*)d_in[17];
  const float* ub2  = (const float*)d_in[18];
  const int* adj    = (const int*)d_in[19];
  const int* invadj = (const int*)d_in[20];
  const int* inidx  = (const int*)d_in[21];
  const int* revidx = (const int*)d_in[22];
  const int* nnodes = (const int*)d_in[23];
  float* out = (float*)d_out;

  float* ws = (float*)d_ws;
  size_t off=0;
  float* enc  = ws+off; off += (size_t)16384*64;
  float* HH1  = ws+off; off += (size_t)16384*64;
  float* sHH1 = ws+off; off += (size_t)16384;
  float* S1   = ws+off; off += (size_t)16384*64;
  float* HH2  = ws+off; off += (size_t)16384*64;
  float* sHH2 = ws+off; off += (size_t)16384;
  float* S2   = ws+off; off += (size_t)16384*64;
  float* nwn  = ws+off; off += (size_t)16384;
  float* C    = ws+off; off += (size_t)512;
  float* nwb  = ws+off; off += (size_t)16384*16;
  float* attn = ws+off; off += (size_t)16384*16;
  float* nrm  = ws+off; off += (size_t)16384*16;
  float* dv   = ws+off; off += (size_t)16384;
  float* P    = ws+off; off += (size_t)2048*64;
  float* wq   = ws+off; off += (size_t)16384*16;
  float* srcq = ws+off; off += (size_t)16384*16;
  float* qv   = ws+off; off += (size_t)16384;
  (void)ws_size; (void)in_sizes; (void)n_in; (void)out_size;

  k_emb<<<64,256,0,stream>>>(emb,encW,encb, P);
  k_enc<<<512,256,0,stream>>>(feat,P,encW,gatW,gatb,gata,gruWh,grub,dW1,db1,dW2,db2, enc,HH1,sHH1,out,C);
  k_layer1<<<1024,256,0,stream>>>(enc,HH1,sHH1,gatW,gatb,gata,gruWx,gruWh,grub,adj,nnodes, S1,HH2,sHH2);
  k_layer2<<<512,256,0,stream>>>(enc,HH2,sHH2,C,gata,gruWx,gruWh,grub,dW1,db1,dW2,db2,adj,nnodes,S1, S2,nwn);
  k_tail<<<512,256,0,stream>>>(S2,nwn,C,uW1,ub1,uW2,ub2,adj,nnodes, nwb,dv);
  k_attn_in<<<1024,256,0,stream>>>(nwb,inidx,invadj,nnodes, attn);
  k_norm<<<1024,256,0,stream>>>(attn,revidx,adj,nnodes, nrm);
  k_prep_dual<<<1024,256,0,stream>>>(nrm,inidx,invadj,nnodes,dv,dem,adj, wq,(int*)srcq,qv,out);
  k_mcf<<<8,1024,0,stream>>>(wq,(const int*)srcq,qv,dem, out);
}

// Round 16
// 272.906 us; speedup vs baseline: 1.2028x; 1.1872x over previous
//
#include <hip/hip_runtime.h>
#include <math.h>

#define VV 2048
#define BIGC 1e9f

__device__ __forceinline__ float wsum64(float v){
  v += __shfl_xor(v, 1, 64);
  v += __shfl_xor(v, 2, 64);
  v += __shfl_xor(v, 4, 64);
  v += __shfl_xor(v, 8, 64);
  v += __shfl_xor(v, 16, 64);
  v += __shfl_xor(v, 32, 64);
  return v;
}
__device__ __forceinline__ float gmax16(float v){
  v = fmaxf(v, __shfl_xor(v, 1, 16));
  v = fmaxf(v, __shfl_xor(v, 2, 16));
  v = fmaxf(v, __shfl_xor(v, 4, 16));
  v = fmaxf(v, __shfl_xor(v, 8, 16));
  return v;
}
__device__ __forceinline__ float gsum16(float v){
  v += __shfl_xor(v, 1, 16);
  v += __shfl_xor(v, 2, 16);
  v += __shfl_xor(v, 4, 16);
  v += __shfl_xor(v, 8, 16);
  return v;
}
__device__ __forceinline__ float sigm(float x){ return 1.f/(1.f+expf(-x)); }

// 8 rows/wave mapping: batch = blk&7 (XCD round-robin), slot = blk>>3 in [0,64)
__device__ __forceinline__ int xcd_base8(int blk, int wid){
  int b = blk & 7, slot = blk >> 3;
  return b*VV + slot*32 + wid*8;
}

// ---------------- K_emb: batch-independent encoder part P[u] = emb_c[u]@encW[:32] + encb ----------------
__global__ void __launch_bounds__(256,2)
k_emb(const float* __restrict__ emb, const float* __restrict__ encW,
      const float* __restrict__ encb, float* __restrict__ P)
{
  __shared__ float EC[4][256];
  int wid = threadIdx.x>>6, lane = threadIdx.x&63;
  int base = blockIdx.x*32 + wid*8;
  #pragma unroll
  for(int r=0;r<8;r++){
    int u = base+r;
    float ev = (lane < 32) ? emb[u*32 + lane] : 0.f;
    float ss = wsum64(ev*ev);
    float sc = (ss > 1.f) ? 1.f/sqrtf(ss) : 1.f;
    if(lane < 32) EC[wid][r*32+lane] = ev*sc;
  }
  float acc[8];
  #pragma unroll
  for(int r=0;r<8;r++) acc[r] = encb[lane];
  for(int k=0;k<32;k++){
    float wv = encW[k*64+lane];
    #pragma unroll
    for(int r=0;r<8;r++) acc[r] += EC[wid][r*32+k]*wv;
  }
  #pragma unroll
  for(int r=0;r<8;r++) P[(base+r)*64+lane] = acc[r];
}

// ---------------- K_enc: per-node encoder (feat part + P) + H1/sH1 (+ folded init in block 0) ----------------
// C layout: [0:64) s1m | [64:128) h2m | [128] sh2m | [384:448) s2m | [448] nwm
__global__ void __launch_bounds__(256,2)
k_enc(const float* __restrict__ feat, const float* __restrict__ P,
      const float* __restrict__ encW,
      const float* __restrict__ gatW, const float* __restrict__ gatb,
      const float* __restrict__ gata,
      const float* __restrict__ gruWh, const float* __restrict__ grub,
      const float* __restrict__ dW1, const float* __restrict__ db1,
      const float* __restrict__ dW2, const float* __restrict__ db2,
      float* __restrict__ enc, float* __restrict__ HH,
      float* __restrict__ sHH, float* __restrict__ out, float* __restrict__ C)
{
  __shared__ float IN[4][128];
  __shared__ float E[4][512];
  __shared__ float hmL[3][64];
  int wid = threadIdx.x >> 6, lane = threadIdx.x & 63;
  int base = xcd_base8(blockIdx.x, wid);
  #pragma unroll
  for(int r=0;r<8;r++){
    int row = base+r;
    if(lane < 16) IN[wid][r*16+lane] = feat[row*16 + lane];
  }
  float acc[8];
  #pragma unroll
  for(int r=0;r<8;r++){
    int u = (base+r) & (VV-1);
    acc[r] = P[u*64+lane];
  }
  for(int k=0;k<16;k++){
    float wv = encW[(32+k)*64+lane];
    #pragma unroll
    for(int r=0;r<8;r++) acc[r] += IN[wid][r*16+k]*wv;
  }
  #pragma unroll
  for(int r=0;r<8;r++){
    enc[(base+r)*64+lane] = acc[r];
    E[wid][r*64+lane] = acc[r];
  }
  float h[8];
  #pragma unroll
  for(int r=0;r<8;r++) h[r] = gatb[lane];
  for(int k=0;k<64;k++){
    float wv = gatW[k*64+lane];
    #pragma unroll
    for(int r=0;r<8;r++) h[r] += E[wid][r*64+k]*wv;
  }
  float gal = gata[lane];
  #pragma unroll
  for(int r=0;r<8;r++){
    float hv = tanhf(h[r]);
    HH[(base+r)*64+lane] = hv;
    float s = wsum64(hv*gal);
    if(lane==0) sHH[base+r] = s;
  }
  // ---- folded init (block 0 only) ----
  if(blockIdx.x == 0){
    if(threadIdx.x < 8) out[threadIdx.x] = 0.f;
    float gb0 = grub[lane], gb1 = grub[64+lane], gb2 = grub[128+lane];
    float z1 = sigm(gb0);
    float s1m = (1.f - z1)*tanhf(gb2);
    if(wid==0){
      C[lane] = s1m;
      float a1 = gatb[lane];
      for(int k=0;k<64;k++) a1 += __shfl(s1m,k,64)*gatW[k*64+lane];
      float h2m = tanhf(a1);
      C[64+lane] = h2m;
      float s = wsum64(h2m*gata[lane]);
      if(lane==0) C[128] = s;
    } else {
      int j = wid-1;
      float a2 = 0.f;
      for(int k=0;k<64;k++) a2 += __shfl(s1m,k,64)*gruWh[k*192+64*j+lane];
      hmL[j][lane] = a2;
    }
    __syncthreads();
    if(wid==0){
      float z2 = sigm(gb0 + hmL[0][lane]);
      float r2 = sigm(gb1 + hmL[1][lane]);
      float c2 = tanhf(gb2 + r2*hmL[2][lane]);
      float s2m = z2*s1m + (1.f-z2)*c2;
      C[384+lane] = s2m;
      int hh = lane & 31;
      float a3 = 0.f;
      for(int k=0;k<64;k++) a3 += __shfl(s2m,k,64)*dW1[k*32+hh];
      float t = tanhf(a3 + db1[hh]);
      float p = (lane < 32) ? t*dW2[hh] : 0.f;
      p = wsum64(p);
      if(lane==0) C[448] = p + db2[0];
    }
  }
}

// Edge-parallel GAT aggregation for one row.
__device__ __forceinline__ float gat_agg(
    int row, int bofs, int nn, float hmask, float smask,
    const float* __restrict__ HH, const float* __restrict__ sHH,
    const int* __restrict__ adj)
{
  int ed = threadIdx.x & 15;
  int a16 = adj[row*16 + ed];
  bool m16 = (a16 == nn);
  float sraw = m16 ? smask : sHH[bofs + a16];
  float mx = gmax16(sraw);
  float e = expf(sraw - mx);
  float den = gsum16(e);
  float p = e/den;
  float hr[16];
  #pragma unroll
  for(int d=0; d<16; d++){
    int a_d = __shfl(a16, d, 16);
    hr[d] = (a_d == nn) ? hmask : HH[(bofs + a_d)*64 + (threadIdx.x & 63)];
  }
  float agg = 0.f;
  #pragma unroll
  for(int d=0; d<16; d++){
    float w = __shfl(p, d, 16);
    agg += w*hr[d];
  }
  return agg;
}

// ---------------- K_layer1: GAT1 agg + GRU1 + H2/sH2. 8 rows/wave, (x,e) b64 interleave ----------------
__global__ void __launch_bounds__(256,2)
k_layer1(const float* __restrict__ enc, const float* __restrict__ HH1,
         const float* __restrict__ sHH1,
         const float* __restrict__ gatW, const float* __restrict__ gatb,
         const float* __restrict__ gata,
         const float* __restrict__ gruWx, const float* __restrict__ gruWh,
         const float* __restrict__ grub,
         const int* __restrict__ adj, const int* __restrict__ num_nodes,
         float* __restrict__ S1, float* __restrict__ HH2,
         float* __restrict__ sHH2)
{
  __shared__ float LXE[4][1024];   // interleaved (x, e) per (r,k)
  __shared__ float LS[4][512];
  int wid = threadIdx.x>>6, lane = threadIdx.x & 63;
  int base = xcd_base8(blockIdx.x, wid);
  int b = base >> 11;
  int bofs = b << 11;
  int nn = num_nodes[b];
  float tb = tanhf(gatb[lane]);
  float gal = gata[lane];
  float cs = wsum64(tb*gal);
  float e[8];
  #pragma unroll
  for(int r=0;r<8;r++){
    int row = base+r;
    float agg = gat_agg(row, bofs, nn, tb, cs - BIGC, HH1, sHH1, adj);
    e[r] = enc[row*64+lane];
    LXE[wid][(r*64+lane)*2]   = agg + e[r];
    LXE[wid][(r*64+lane)*2+1] = e[r];
  }
  const float2* LXE2 = (const float2*)&LXE[wid][0];
  float ax[8][3], ah[8][3];
  #pragma unroll
  for(int r=0;r<8;r++)
    #pragma unroll
    for(int j=0;j<3;j++){ ax[r][j]=0.f; ah[r][j]=0.f; }
  for(int k=0;k<64;k++){
    float wx0 = gruWx[k*192+lane];
    float wx1 = gruWx[k*192+64+lane];
    float wx2 = gruWx[k*192+128+lane];
    float wh0 = gruWh[k*192+lane];
    float wh1 = gruWh[k*192+64+lane];
    float wh2 = gruWh[k*192+128+lane];
    #pragma unroll
    for(int r=0;r<8;r++){
      float2 xe = LXE2[r*64+k];
      ax[r][0] += xe.x*wx0; ax[r][1] += xe.x*wx1; ax[r][2] += xe.x*wx2;
      ah[r][0] += xe.y*wh0; ah[r][1] += xe.y*wh1; ah[r][2] += xe.y*wh2;
    }
  }
  float gb0 = grub[lane], gb1 = grub[64+lane], gb2 = grub[128+lane];
  #pragma unroll
  for(int r=0;r<8;r++){
    float z = sigm(ax[r][0]+gb0+ah[r][0]);
    float rr = sigm(ax[r][1]+gb1+ah[r][1]);
    float c = tanhf(ax[r][2]+gb2+rr*ah[r][2]);
    float s1 = z*e[r] + (1.f-z)*c;
    S1[(base+r)*64+lane] = s1;
    LS[wid][r*64+lane] = s1;
  }
  float h[8];
  #pragma unroll
  for(int r=0;r<8;r++) h[r] = gatb[lane];
  for(int k=0;k<64;k++){
    float wv = gatW[k*64+lane];
    #pragma unroll
    for(int r=0;r<8;r++) h[r] += LS[wid][r*64+k]*wv;
  }
  #pragma unroll
  for(int r=0;r<8;r++){
    float hv = tanhf(h[r]);
    HH2[(base+r)*64+lane] = hv;
    float s = wsum64(hv*gal);
    if(lane==0) sHH2[base+r] = s;
  }
}

// ---------------- K_layer2: GAT2 agg + GRU2 + decoder. 8 rows/wave, (x,s1) b64 interleave ----------------
__global__ void __launch_bounds__(256,2)
k_layer2(const float* __restrict__ enc, const float* __restrict__ HH2,
         const float* __restrict__ sHH2, const float* __restrict__ C,
         const float* __restrict__ gata,
         const float* __restrict__ gruWx, const float* __restrict__ gruWh,
         const float* __restrict__ grub,
         const float* __restrict__ dW1, const float* __restrict__ db1,
         const float* __restrict__ dW2, const float* __restrict__ db2,
         const int* __restrict__ adj, const int* __restrict__ num_nodes,
         const float* __restrict__ S1,
         float* __restrict__ S2, float* __restrict__ nwn)
{
  __shared__ float LXS[4][1024];
  __shared__ float LS2[4][512];
  int wid = threadIdx.x>>6, lane = threadIdx.x & 63;
  int base = xcd_base8(blockIdx.x, wid);
  int b = base >> 11;
  int bofs = b << 11;
  int nn = num_nodes[b];
  float h2m = C[64+lane];
  float sh2m = C[128];
  float s1v[8];
  #pragma unroll
  for(int r=0;r<8;r++){
    int row = base+r;
    float agg = gat_agg(row, bofs, nn, h2m, sh2m - BIGC, HH2, sHH2, adj);
    float x = agg + enc[row*64+lane];
    s1v[r] = S1[row*64+lane];
    LXS[wid][(r*64+lane)*2]   = x;
    LXS[wid][(r*64+lane)*2+1] = s1v[r];
  }
  const float2* LXS2 = (const float2*)&LXS[wid][0];
  float ax[8][3], am[8][3];
  #pragma unroll
  for(int r=0;r<8;r++)
    #pragma unroll
    for(int j=0;j<3;j++){ ax[r][j]=0.f; am[r][j]=0.f; }
  for(int k=0;k<64;k++){
    float wx0 = gruWx[k*192+lane];
    float wx1 = gruWx[k*192+64+lane];
    float wx2 = gruWx[k*192+128+lane];
    float wh0 = gruWh[k*192+lane];
    float wh1 = gruWh[k*192+64+lane];
    float wh2 = gruWh[k*192+128+lane];
    #pragma unroll
    for(int r=0;r<8;r++){
      float2 xs = LXS2[r*64+k];
      ax[r][0] += xs.x*wx0; ax[r][1] += xs.x*wx1; ax[r][2] += xs.x*wx2;
      am[r][0] += xs.y*wh0; am[r][1] += xs.y*wh1; am[r][2] += xs.y*wh2;
    }
  }
  float gb0 = grub[lane], gb1 = grub[64+lane], gb2 = grub[128+lane];
  #pragma unroll
  for(int r=0;r<8;r++){
    float z = sigm(ax[r][0]+gb0+am[r][0]);
    float rr = sigm(ax[r][1]+gb1+am[r][1]);
    float c = tanhf(ax[r][2]+gb2+rr*am[r][2]);
    float s2 = z*s1v[r] + (1.f-z)*c;
    S2[(base+r)*64+lane] = s2;
    LS2[wid][r*64+lane] = s2;
  }
  int h = lane & 31;
  float accd[8];
  #pragma unroll
  for(int r=0;r<8;r++) accd[r]=0.f;
  for(int k=0;k<64;k++){
    float wv = dW1[k*32+h];
    #pragma unroll
    for(int r=0;r<8;r++) accd[r] += LS2[wid][r*64+k]*wv;
  }
  float b1 = db1[h], w2 = dW2[h], b2 = db2[0];
  #pragma unroll
  for(int r=0;r<8;r++){
    float t = tanhf(accd[r] + b1);
    float p = (lane<32) ? t*w2 : 0.f;
    p = wsum64(p);
    if(lane==0) nwn[base+r] = p + b2;
  }
}

// ---------------- K_tail: node_states gather + dual head + nw gather. 8 rows/wave ----------------
__global__ void __launch_bounds__(256,2)
k_tail(const float* __restrict__ S2, const float* __restrict__ nwn,
       const float* __restrict__ C,
       const float* __restrict__ uW1, const float* __restrict__ ub1,
       const float* __restrict__ uW2, const float* __restrict__ ub2,
       const int* __restrict__ adj, const int* __restrict__ num_nodes,
       float* __restrict__ nw, float* __restrict__ dv)
{
  __shared__ float LN[4][512];
  int wid = threadIdx.x>>6, lane = threadIdx.x&63;
  int base = xcd_base8(blockIdx.x, wid);
  int b = base>>11;
  int bofs = b<<11;
  int nn = num_nodes[b];
  float s2m = C[384+lane];
  float nwm = C[448];
  #pragma unroll
  for(int r=0;r<8;r++){
    int row = base+r;
    int ed = lane & 15;
    int a16 = adj[row*16 + ed];
    float hr[16];
    #pragma unroll
    for(int d=0;d<16;d++){
      int a_d = __shfl(a16, d, 16);
      hr[d] = (a_d==nn) ? s2m : S2[(bofs+a_d)*64+lane];
    }
    float ns = 0.f;
    #pragma unroll
    for(int d=0;d<16;d++) ns += hr[d];
    LN[wid][r*64+lane] = ns;
    if(lane < 16){
      bool m = (a16==nn);
      nw[row*16+lane] = m ? nwm : nwn[bofs+a16];
    }
  }
  int h = lane & 31;
  float acc[8];
  #pragma unroll
  for(int r=0;r<8;r++) acc[r]=0.f;
  for(int k=0;k<64;k++){
    float wv = uW1[k*32+h];
    #pragma unroll
    for(int r=0;r<8;r++) acc[r] += LN[wid][r*64+k]*wv;
  }
  float b1 = ub1[h], w2 = uW2[h], b2 = ub2[0];
  #pragma unroll
  for(int r=0;r<8;r++){
    float t = tanhf(acc[r] + b1);
    float p = (lane<32) ? t*w2 : 0.f;
    p = wsum64(p);
    if(lane==0) dv[base+r] = p + b2;
  }
}

// ---------------- K5: incoming gather + softmax(in). edge-parallel ----------------
__global__ void k_attn_in(const float* __restrict__ nw, const int* __restrict__ in_idx,
                          const int* __restrict__ inv_adj, const int* __restrict__ num_nodes,
                          float* __restrict__ attn_in)
{
  int b = blockIdx.x & 7, slot = blockIdx.x >> 3;
  int e = b*32768 + slot*256 + threadIdx.x;
  int nn = num_nodes[b];
  float w = nw[b*32768 + in_idx[e]];
  bool im = (inv_adj[e]==nn);
  float sc = w - (im ? BIGC : 0.f);
  float mx = gmax16(sc);
  float ex = expf(sc-mx);
  float den = gsum16(ex);
  attn_in[e] = ex/den;
}

// ---------------- K6: rev gather + softmax -> normalized. edge-parallel ----------------
__global__ void k_norm(const float* __restrict__ attn_in, const int* __restrict__ rev_idx,
                       const int* __restrict__ adj, const int* __restrict__ num_nodes,
                       float* __restrict__ normalized)
{
  int b = blockIdx.x & 7, slot = blockIdx.x >> 3;
  int e = b*32768 + slot*256 + threadIdx.x;
  int nn = num_nodes[b];
  float g = attn_in[b*32768 + rev_idx[e]];
  bool m = (adj[e]==nn);
  float sc = g - (m ? BIGC : 0.f);
  float mx = gmax16(sc);
  float ex = expf(sc-mx);
  float den = gsum16(ex);
  normalized[e] = ex/den;
}

// ---------------- K_prep_dual: mcf tables + qv AND dual iterations, one launch ----------------
__global__ void k_prep_dual(const float* __restrict__ normalized, const int* __restrict__ in_idx,
                            const int* __restrict__ inv_adj, const int* __restrict__ num_nodes,
                            const float* __restrict__ dual_vars, const float* __restrict__ demands,
                            const int* __restrict__ adj,
                            float* __restrict__ wq, int* __restrict__ srcq,
                            float* __restrict__ qv, float* __restrict__ out)
{
  int b = blockIdx.x & 7, slot = blockIdx.x >> 3;
  int e = b*32768 + slot*256 + threadIdx.x;
  int v = e >> 4;
  int nn = num_nodes[b];
  // --- mcf prep part ---
  int ii = in_idx[e];
  bool im = (inv_adj[e]==nn);
  wq[e] = im ? 0.f : normalized[b*32768 + ii];
  srcq[e] = ii >> 4;
  float nv = normalized[e];
  float qq = gsum16(nv*nv);
  if((e & 15) == 0) qv[v] = qq;
  // --- dual part ---
  float dvv = dual_vars[v];
  int a = adj[e];
  bool m = (a==nn);
  float dvn = dual_vars[(b<<11)+a];
  float dd = m ? (-dvv) : dvn;
  float valid = m ? 0.f : 1.f;
  float f=0.f, acc=0.f;
  #pragma unroll
  for(int it=0; it<10; ++it){
    float grad = 2.f*f + dd;
    acc = 0.9f*acc + 0.01f*grad;
    f = fmaxf(f-acc, 0.f)*valid;
  }
  float contrib = -(f*f + dd*f);
  if((e & 15) == 0) contrib += dvv * demands[v];
  float s = wsum64(contrib);
  __shared__ float red[4];
  int wid = threadIdx.x>>6, lane = threadIdx.x&63;
  if(lane==0) red[wid]=s;
  __syncthreads();
  if(threadIdx.x==0) atomicAdd(out+b, red[0]+red[1]+red[2]+red[3]);
}

// ---------------- K7: MCF iterations via float4/int4 tables + LDS state ----------------
__global__ void __launch_bounds__(1024,1)
k_mcf(const float* __restrict__ wq, const int* __restrict__ srcq,
      const float* __restrict__ qv, const float* __restrict__ demands,
      float* __restrict__ out)
{
  __shared__ float T[2][2048];
  int b = blockIdx.x; int tid = threadIdx.x;  // 1024 threads, 2 nodes/thread
  const float4* w4 = (const float4*)(wq + b*32768);
  const int4*   s4 = (const int4*)(srcq + b*32768);
  float sup[2], q[2];
  float4 wr[2][4]; int4 sr[2][4];
  #pragma unroll
  for(int s=0;s<2;s++){
    int vi = tid + s*1024;
    sup[s] = fmaxf(-demands[b*2048+vi], 0.f);
    q[s] = qv[b*2048+vi];
    #pragma unroll
    for(int g=0;g<4;g++){ wr[s][g] = w4[vi*4+g]; sr[s][g] = s4[vi*4+g]; }
    T[0][vi] = sup[s];
  }
  __syncthreads();
  int cur = 0;
  for(int it=0; it<10; ++it){
    float nt[2];
    #pragma unroll
    for(int s=0;s<2;s++){
      float acc = sup[s];
      #pragma unroll
      for(int g=0;g<4;g++){
        float4 w = wr[s][g]; int4 sc = sr[s][g];
        acc += w.x*T[cur][sc.x] + w.y*T[cur][sc.y] + w.z*T[cur][sc.z] + w.w*T[cur][sc.w];
      }
      nt[s] = acc;
    }
    #pragma unroll
    for(int s=0;s<2;s++) T[cur^1][tid+s*1024] = nt[s];
    __syncthreads();
    cur ^= 1;
  }
  float fc = q[0]*T[cur][tid]*T[cur][tid] + q[1]*T[cur][tid+1024]*T[cur][tid+1024];
  fc = wsum64(fc);
  __shared__ float red[16];
  int wid = tid>>6, lane = tid&63;
  if(lane==0) red[wid]=fc;
  __syncthreads();
  if(tid==0){
    float s=0.f;
    for(int i=0;i<16;i++) s+=red[i];
    atomicAdd(out+b, s);
  }
}

extern "C" void kernel_launch(void* const* d_in, const int* in_sizes, int n_in,
                              void* d_out, int out_size, void* d_ws, size_t ws_size,
                              hipStream_t stream)
{
  const float* feat = (const float*)d_in[0];
  const float* dem  = (const float*)d_in[1];
  const float* emb  = (const float*)d_in[2];
  const float* encW = (const float*)d_in[3];
  const float* encb = (const float*)d_in[4];
  const float* gatW = (const float*)d_in[5];
  const float* gatb = (const float*)d_in[6];
  const float* gata = (const float*)d_in[7];
  const float* gruWx= (const float*)d_in[8];
  const float* gruWh= (const float*)d_in[9];
  const float* grub = (const float*)d_in[10];
  const float* dW1  = (const float*)d_in[11];
  const float* db1  = (const float*)d_in[12];
  const float* dW2  = (const float*)d_in[13];
  const float* db2  = (const float*)d_in[14];
  const float* uW1  = (const float*)d_in[15];
  const float* ub1  = (const float*)d_in[16];
  const float* uW2  = (const float*)d_in[17];
  const float* ub2  = (const float*)d_in[18];
  const int* adj    = (const int*)d_in[19];
  const int* invadj = (const int*)d_in[20];
  const int* inidx  = (const int*)d_in[21];
  const int* revidx = (const int*)d_in[22];
  const int* nnodes = (const int*)d_in[23];
  float* out = (float*)d_out;

  float* ws = (float*)d_ws;
  size_t off=0;
  float* enc  = ws+off; off += (size_t)16384*64;
  float* HH1  = ws+off; off += (size_t)16384*64;
  float* sHH1 = ws+off; off += (size_t)16384;
  float* S1   = ws+off; off += (size_t)16384*64;
  float* HH2  = ws+off; off += (size_t)16384*64;
  float* sHH2 = ws+off; off += (size_t)16384;
  float* S2   = ws+off; off += (size_t)16384*64;
  float* nwn  = ws+off; off += (size_t)16384;
  float* C    = ws+off; off += (size_t)512;
  float* nwb  = ws+off; off += (size_t)16384*16;
  float* attn = ws+off; off += (size_t)16384*16;
  float* nrm  = ws+off; off += (size_t)16384*16;
  float* dv   = ws+off; off += (size_t)16384;
  float* P    = ws+off; off += (size_t)2048*64;
  float* wq   = ws+off; off += (size_t)16384*16;
  float* srcq = ws+off; off += (size_t)16384*16;
  float* qv   = ws+off; off += (size_t)16384;
  (void)ws_size; (void)in_sizes; (void)n_in; (void)out_size;

  k_emb<<<64,256,0,stream>>>(emb,encW,encb, P);
  k_enc<<<512,256,0,stream>>>(feat,P,encW,gatW,gatb,gata,gruWh,grub,dW1,db1,dW2,db2, enc,HH1,sHH1,out,C);
  k_layer1<<<512,256,0,stream>>>(enc,HH1,sHH1,gatW,gatb,gata,gruWx,gruWh,grub,adj,nnodes, S1,HH2,sHH2);
  k_layer2<<<512,256,0,stream>>>(enc,HH2,sHH2,C,gata,gruWx,gruWh,grub,dW1,db1,dW2,db2,adj,nnodes,S1, S2,nwn);
  k_tail<<<512,256,0,stream>>>(S2,nwn,C,uW1,ub1,uW2,ub2,adj,nnodes, nwb,dv);
  k_attn_in<<<1024,256,0,stream>>>(nwb,inidx,invadj,nnodes, attn);
  k_norm<<<1024,256,0,stream>>>(attn,revidx,adj,nnodes, nrm);
  k_prep_dual<<<1024,256,0,stream>>>(nrm,inidx,invadj,nnodes,dv,dem,adj, wq,(int*)srcq,qv,out);
  k_mcf<<<8,1024,0,stream>>>(wq,(const int*)srcq,qv,dem, out);
}